// Round 7
// baseline (295.784 us; speedup 1.0000x reference)
//
#include <hip/hip_runtime.h>

#define NB 147456   // C*C*KH*KW per sample
#define ZD 256
#define BSZ 32
#define CCH 128

typedef __attribute__((ext_vector_type(8))) short short8;
typedef __attribute__((ext_vector_type(16))) float floatx16;

__device__ __forceinline__ unsigned short f2bf(float f) {
    unsigned int u = __float_as_uint(f);
    return (unsigned short)((u + 0x7fffu + ((u >> 16) & 1u)) >> 16);
}
// pack hi16(lo),hi16(hi) -> one dword (two bf16, truncating convert)
__device__ __forceinline__ unsigned pk(unsigned hi, unsigned lo) {
    return __builtin_amdgcn_perm(hi, lo, 0x07060302u);
}

// ---- K1: h = relu(z@W+b); BN over batch; affine; bf16 Wk natural [b][n] -----------------------
// MFMA 32x32x16, M=32 batch. No LDS, no barriers: A-frags (z) held in 64 VGPRs, loaded via L2
// gather once; B (dense_w) streamed with per-lane base + wave-uniform offsets, depth-2 prefetch.
__global__ __launch_bounds__(256) void hyper_mfma(
    const float* __restrict__ z, const float* __restrict__ dw,
    const float* __restrict__ db, const float* __restrict__ gamma,
    const float* __restrict__ beta, unsigned short* __restrict__ wkn)
{
    int t = threadIdx.x;
    int wid = t >> 6, lane = t & 63;
    int n = blockIdx.x * 128 + wid * 32 + (lane & 31);
    int klane = lane >> 5;
    int m = lane & 31;

    // A-frags: afrag[s] holds z[m][s*16 + klane*8 .. +7] as bf16 (layout verified in R6)
    short8 afrag[16];
    const float* zp = z + m * 256 + klane * 8;
#pragma unroll
    for (int s = 0; s < 16; s++) {
        float4 a0 = *(const float4*)(zp + s * 16);
        float4 a1 = *(const float4*)(zp + s * 16 + 4);
        uint4 u;
        u.x = pk(__float_as_uint(a0.y), __float_as_uint(a0.x));
        u.y = pk(__float_as_uint(a0.w), __float_as_uint(a0.z));
        u.z = pk(__float_as_uint(a1.y), __float_as_uint(a1.x));
        u.w = pk(__float_as_uint(a1.w), __float_as_uint(a1.z));
        afrag[s] = *(short8*)&u;
    }

    floatx16 acc;
#pragma unroll
    for (int r = 0; r < 16; r++) acc[r] = 0.f;

    // per-lane base: loop offsets are wave-uniform multiples of NB
    const float* dwp = dw + (size_t)(klane * 8) * NB + n;

    unsigned ba[8], bb[8];
#define LOADB(BUF, S)                                                        \
    _Pragma("unroll") for (int j = 0; j < 8; j++)                            \
        BUF[j] = __float_as_uint(dwp[(size_t)((S) * 16 + j) * NB]);
#define DOMFMA(BUF, S)                                                       \
    {                                                                        \
        uint4 u;                                                             \
        u.x = pk(BUF[1], BUF[0]); u.y = pk(BUF[3], BUF[2]);                  \
        u.z = pk(BUF[5], BUF[4]); u.w = pk(BUF[7], BUF[6]);                  \
        acc = __builtin_amdgcn_mfma_f32_32x32x16_bf16(                       \
            afrag[S], *(short8*)&u, acc, 0, 0, 0);                           \
    }
    LOADB(ba, 0)
#pragma unroll
    for (int s = 0; s < 16; s += 2) {
        LOADB(bb, s + 1)
        DOMFMA(ba, s)
        if (s + 2 < 16) LOADB(ba, s + 2)
        DOMFMA(bb, s + 1)
    }
#undef LOADB
#undef DOMFMA

    // BN epilogue: C rows = batch; lane pairs (lane, lane^32) hold all 32 rows of column n
    float bias = db[n];
    float h[16], sp = 0.f, qp = 0.f;
#pragma unroll
    for (int r = 0; r < 16; r++) {
        float v = fmaxf(acc[r] + bias, 0.f);
        h[r] = v; sp += v; qp += v * v;
    }
    sp += __shfl_xor(sp, 32, 64);
    qp += __shfl_xor(qp, 32, 64);
    float mn = sp * (1.f / 32.f);
    float var = fmaxf(qp * (1.f / 32.f) - mn * mn, 0.f);
    float sc = gamma[n] / (sqrtf(var) + 1e-6f);
    float bt = beta[n];
#pragma unroll
    for (int r = 0; r < 16; r++) {
        int brow = (r & 3) + 8 * (r >> 2) + 4 * klane;
        wkn[(size_t)brow * NB + n] = f2bf(sc * (h[r] - mn) + bt);
    }
}

// ---- fused: blocks 0..255 repack wkn->wkt; blocks 256..1279 transpose x -> xT bf16 -----------
__global__ __launch_bounds__(256) void repack_xt(
    const unsigned short* __restrict__ wkn, unsigned short* __restrict__ wkt,
    const float* __restrict__ x, unsigned short* __restrict__ xb16)
{
    __shared__ char lmem[16 * 580 * 4];
    int t = threadIdx.x;
    if (blockIdx.x < 256) {
        unsigned int* lt = (unsigned int*)lmem;   // [16][580]
        int b = blockIdx.x >> 3;
        int s0 = (blockIdx.x & 7) * 16;
        const unsigned int* src = (const unsigned int*)wkn + ((size_t)b * NB >> 1) + (size_t)s0 * 576;
#pragma unroll
        for (int i = 0; i < 36; i++) {
            int idx = t + i * 256;
            int si = idx / 576;
            int j2 = idx - si * 576;
            lt[si * 580 + j2] = src[(size_t)si * 576 + j2];
        }
        __syncthreads();
        const unsigned short* ls = (const unsigned short*)lt;
#pragma unroll
        for (int i = 0; i < 9; i++) {
            int tau = t + i * 256;
            int half = tau & 1;
            int unit = tau >> 1;
            int uv = unit >> 7;
            int f = unit & 127;
            int col = f * 9 + uv;
            unsigned short v[8];
#pragma unroll
            for (int ss = 0; ss < 8; ss++)
                v[ss] = ls[(half * 8 + ss) * 1160 + col];
            uint4 o;
            o.x = v[0] | ((unsigned)v[1] << 16);
            o.y = v[2] | ((unsigned)v[3] << 16);
            o.z = v[4] | ((unsigned)v[5] << 16);
            o.w = v[6] | ((unsigned)v[7] << 16);
            ((uint4*)wkt)[((((size_t)b * 9 + uv) * 128 + f) * 16) + (s0 >> 3) + half] = o;
        }
    } else {
        unsigned short* lx = (unsigned short*)lmem;   // [32][130]
        int idx = blockIdx.x - 256;
        int p = idx & 31;
        int b = idx >> 5;
        const float* xp = x + (size_t)b * CCH * 1024 + p * 32;
#pragma unroll
        for (int i = 0; i < 16; i++) {
            int ii = t + i * 256;
            int s = ii >> 5;
            int q = ii & 31;
            lx[q * 130 + s] = f2bf(xp[(size_t)s * 1024 + q]);
        }
        __syncthreads();
#pragma unroll
        for (int i = 0; i < 2; i++) {
            int tau = t + i * 256;
            int q = tau >> 4;
            int ch = tau & 15;
            const unsigned short* r = &lx[q * 130 + ch * 8];
            uint4 o;
            o.x = r[0] | ((unsigned)r[1] << 16);
            o.y = r[2] | ((unsigned)r[3] << 16);
            o.z = r[4] | ((unsigned)r[5] << 16);
            o.w = r[6] | ((unsigned)r[7] << 16);
            ((uint4*)xb16)[((((size_t)b * 32 + p) * 32) + q) * 16 + ch] = o;
        }
    }
}

// ---- conv: 256 thr = 4 waves (2 f-halves x 2 row-pairs), p-tile = 4 rows, 256 blocks ----------
// Depth-1 double-buffered A prefetch. XCD-swizzled: 4 samples/XCD (Wk slice L2-resident).
__global__ __launch_bounds__(256) void conv_mfma(
    const float* __restrict__ x, const unsigned short* __restrict__ xb16,
    const unsigned short* __restrict__ wkt, const float* __restrict__ cb,
    float* __restrict__ out)
{
    __shared__ short8 lds8[6 * 34 * 17];      // 55.5 KB: rows p0-1..p0+4, col stride 17 chunks
    int t = threadIdx.x;
    int w = blockIdx.x;                       // 256 blocks
    int xcd = w & 7, slot = w >> 3;
    int b = (xcd << 2) | (slot & 3);
    int p0 = (slot >> 2) * 4;
    int wid = t >> 6, lane = t & 63;
    int fbase = (wid & 1) * 64;
    int rbase = (wid >> 1) * 2;
    int qcol = lane & 31, klane = lane >> 5;

    if (t < 192) {                            // zero halo cols 0 and 33, 6 rows
        int r = t >> 5;
        int col = ((t >> 4) & 1) ? 33 : 0;
        int ch = t & 15;
        short8 zz = { 0, 0, 0, 0, 0, 0, 0, 0 };
        lds8[(r * 34 + col) * 17 + ch] = zz;
    }
    const uint4* xsrc = (const uint4*)xb16;
#pragma unroll
    for (int i = 0; i < 12; i++) {            // stage 6 rows x 32 q x 16 ch = 3072 uint4
        int tau = t + i * 256;
        int ch = tau & 15;
        int q = (tau >> 4) & 31;
        int r = tau >> 9;                     // 0..5
        int prow = p0 - 1 + r;
        uint4 v = make_uint4(0, 0, 0, 0);
        if (prow >= 0 && prow < 32)
            v = xsrc[((((size_t)b * 32 + prow) * 32) + q) * 16 + ch];
        *(uint4*)&lds8[(r * 34 + q + 1) * 17 + ch] = v;
    }
    __syncthreads();

    floatx16 acc[2][2];
#pragma unroll
    for (int mi = 0; mi < 2; mi++)
#pragma unroll
        for (int ni = 0; ni < 2; ni++)
#pragma unroll
            for (int r = 0; r < 16; r++) acc[mi][ni][r] = 0.f;

    const short8* A8 = (const short8*)wkt + ((size_t)b * 9 << 11);
    short8 Abuf0[6], Abuf1[6];

#define LOAD6(BUF, ST)                                                        \
    {                                                                         \
        int v_ = (ST) >> 3, ks_ = (ST) & 7;                                   \
        int ko_ = ks_ * 2 + klane;                                            \
        _Pragma("unroll") for (int u_ = 0; u_ < 3; u_++) {                    \
            const short8* Au_ = A8 + ((size_t)(u_ * 3 + v_) << 11);           \
            BUF[u_ * 2]     = Au_[(fbase + qcol) * 16 + ko_];                 \
            BUF[u_ * 2 + 1] = Au_[(fbase + 32 + qcol) * 16 + ko_];            \
        }                                                                     \
    }
#define COMPUTE(BUF, ST)                                                      \
    {                                                                         \
        int v_ = (ST) >> 3, ks_ = (ST) & 7;                                   \
        int ko_ = ks_ * 2 + klane;                                            \
        short8 br[4];                                                         \
        _Pragma("unroll") for (int r_ = 0; r_ < 4; r_++)                      \
            br[r_] = lds8[((rbase + r_) * 34 + qcol + v_) * 17 + ko_];        \
        _Pragma("unroll") for (int u_ = 0; u_ < 3; u_++) {                    \
            acc[0][0] = __builtin_amdgcn_mfma_f32_32x32x16_bf16(              \
                BUF[u_ * 2], br[u_], acc[0][0], 0, 0, 0);                     \
            acc[0][1] = __builtin_amdgcn_mfma_f32_32x32x16_bf16(              \
                BUF[u_ * 2], br[u_ + 1], acc[0][1], 0, 0, 0);                 \
            acc[1][0] = __builtin_amdgcn_mfma_f32_32x32x16_bf16(              \
                BUF[u_ * 2 + 1], br[u_], acc[1][0], 0, 0, 0);                 \
            acc[1][1] = __builtin_amdgcn_mfma_f32_32x32x16_bf16(              \
                BUF[u_ * 2 + 1], br[u_ + 1], acc[1][1], 0, 0, 0);             \
        }                                                                     \
    }

    LOAD6(Abuf0, 0)
    for (int st = 0; st < 24; st += 2) {
        LOAD6(Abuf1, st + 1)
        COMPUTE(Abuf0, st)
        if (st + 2 < 24) LOAD6(Abuf0, st + 2)
        COMPUTE(Abuf1, st + 1)
    }
#undef LOAD6
#undef COMPUTE

    const size_t xb = (size_t)b * CCH * 1024;
    int prow0 = p0 + rbase;
#pragma unroll
    for (int mi = 0; mi < 2; mi++)
#pragma unroll
    for (int ni = 0; ni < 2; ni++) {
        int p = prow0 + ni;
#pragma unroll
        for (int r = 0; r < 16; r++) {
            int fl = (r & 3) + 8 * (r >> 2) + 4 * klane;
            int f = fbase + mi * 32 + fl;
            size_t idx = xb + (size_t)f * 1024 + p * 32 + qcol;
            out[idx] = acc[mi][ni][r] + x[idx] + cb[f];
        }
    }
}

extern "C" void kernel_launch(void* const* d_in, const int* in_sizes, int n_in,
                              void* d_out, int out_size, void* d_ws, size_t ws_size,
                              hipStream_t stream) {
    const float* x     = (const float*)d_in[0];
    const float* z     = (const float*)d_in[1];
    const float* dw    = (const float*)d_in[2];
    const float* db    = (const float*)d_in[3];
    const float* gamma = (const float*)d_in[4];
    const float* beta  = (const float*)d_in[5];
    const float* cb    = (const float*)d_in[6];
    float* out = (float*)d_out;

    unsigned short* wkn  = (unsigned short*)d_ws;                                       // 9.44 MB
    unsigned short* wkt  = (unsigned short*)((char*)d_ws + (size_t)BSZ * NB * 2);       // 9.44 MB
    unsigned short* xb16 = (unsigned short*)((char*)d_ws + (size_t)BSZ * NB * 4);       // 8.4 MB

    hyper_mfma<<<NB / 128, 256, 0, stream>>>(z, dw, db, gamma, beta, wkn);
    repack_xt<<<256 + 1024, 256, 0, stream>>>(wkn, wkt, x, xb16);
    conv_mfma<<<256, 256, 0, stream>>>(x, xb16, wkt, cb, out);
}

// Round 8
// 289.263 us; speedup vs baseline: 1.0225x; 1.0225x over previous
//
#include <hip/hip_runtime.h>

#define NB 147456   // C*C*KH*KW per sample
#define ZD 256
#define BSZ 32
#define CCH 128

typedef __attribute__((ext_vector_type(8))) short short8;
typedef __attribute__((ext_vector_type(16))) float floatx16;

__device__ __forceinline__ unsigned short f2bf(float f) {
    unsigned int u = __float_as_uint(f);
    return (unsigned short)((u + 0x7fffu + ((u >> 16) & 1u)) >> 16);
}
// pack hi16(lo),hi16(hi) -> one dword (two bf16, truncating convert)
__device__ __forceinline__ unsigned pk(unsigned hi, unsigned lo) {
    return __builtin_amdgcn_perm(hi, lo, 0x07060302u);
}

// ---- K1: h = relu(z@W+b); BN over batch; affine; bf16 Wk natural [b][n] -----------------------
// MFMA 32x32x16, M=32 batch. Wave = 128 cols as 4 interleaved tiles (tile t = cols 4*L+t):
// B stream is global_load_dwordx4 (16 B/lane), 4x fewer VMEM instrs than scalar-dword version.
// 64-thr blocks x 1152: 4.5 waves/CU, 1.11x tail. Depth-2 prefetch (16 KB in flight/wave).
__global__ __launch_bounds__(64) void hyper_mfma(
    const float* __restrict__ z, const float* __restrict__ dw,
    const float* __restrict__ db, const float* __restrict__ gamma,
    const float* __restrict__ beta, unsigned short* __restrict__ wkn)
{
    int lane = threadIdx.x;                   // one wave per block
    int L = lane & 31;
    int klane = lane >> 5;
    int n0 = blockIdx.x * 128 + 4 * L;        // this lane's col group; tile t owns n0+t

    // A-frags: afrag[s] = z[m=L][s*16 + klane*8 .. +7] as bf16
    short8 afrag[16];
    const float* zp = z + L * 256 + klane * 8;
#pragma unroll
    for (int s = 0; s < 16; s++) {
        float4 a0 = *(const float4*)(zp + s * 16);
        float4 a1 = *(const float4*)(zp + s * 16 + 4);
        uint4 u;
        u.x = pk(__float_as_uint(a0.y), __float_as_uint(a0.x));
        u.y = pk(__float_as_uint(a0.w), __float_as_uint(a0.z));
        u.z = pk(__float_as_uint(a1.y), __float_as_uint(a1.x));
        u.w = pk(__float_as_uint(a1.w), __float_as_uint(a1.z));
        afrag[s] = *(short8*)&u;
    }

    floatx16 acc[4];
#pragma unroll
    for (int t = 0; t < 4; t++)
#pragma unroll
        for (int r = 0; r < 16; r++) acc[t][r] = 0.f;

    const float* dwp = dw + (size_t)(klane * 8) * NB + n0;

    unsigned ba[8][4], bb[8][4];
#define LOADB(BUF, S)                                                         \
    _Pragma("unroll") for (int j = 0; j < 8; j++)                             \
        *(uint4*)&BUF[j][0] = *(const uint4*)(dwp + (size_t)((S) * 16 + j) * NB);
#define DOMFMA(BUF, S)                                                        \
    _Pragma("unroll") for (int t = 0; t < 4; t++) {                           \
        uint4 u;                                                              \
        u.x = pk(BUF[1][t], BUF[0][t]); u.y = pk(BUF[3][t], BUF[2][t]);       \
        u.z = pk(BUF[5][t], BUF[4][t]); u.w = pk(BUF[7][t], BUF[6][t]);       \
        acc[t] = __builtin_amdgcn_mfma_f32_32x32x16_bf16(                     \
            afrag[S], *(short8*)&u, acc[t], 0, 0, 0);                         \
    }
    LOADB(ba, 0)
#pragma unroll
    for (int s = 0; s < 16; s += 2) {
        LOADB(bb, s + 1)
        DOMFMA(ba, s)
        if (s + 2 < 16) LOADB(ba, s + 2)
        DOMFMA(bb, s + 1)
    }
#undef LOADB
#undef DOMFMA

    // BN epilogue per tile-column; rows split between lane and lane^32
    float4 bias = *(const float4*)(db + n0);
    float4 gmm  = *(const float4*)(gamma + n0);
    float4 btt  = *(const float4*)(beta + n0);
    float bias_a[4] = { bias.x, bias.y, bias.z, bias.w };
    float gm_a[4]   = { gmm.x, gmm.y, gmm.z, gmm.w };
    float bt_a[4]   = { btt.x, btt.y, btt.z, btt.w };

    float sc_a[4], mn_a[4];
#pragma unroll
    for (int t = 0; t < 4; t++) {
        float sp = 0.f, qp = 0.f;
#pragma unroll
        for (int r = 0; r < 16; r++) {
            float v = fmaxf(acc[t][r] + bias_a[t], 0.f);
            acc[t][r] = v;
            sp += v; qp += v * v;
        }
        sp += __shfl_xor(sp, 32, 64);
        qp += __shfl_xor(qp, 32, 64);
        float mn = sp * (1.f / 32.f);
        float var = fmaxf(qp * (1.f / 32.f) - mn * mn, 0.f);
        mn_a[t] = mn;
        sc_a[t] = gm_a[t] / (sqrtf(var) + 1e-6f);
    }

#pragma unroll
    for (int r = 0; r < 16; r++) {
        int brow = (r & 3) + 8 * (r >> 2) + 4 * klane;
        float w0 = sc_a[0] * (acc[0][r] - mn_a[0]) + bt_a[0];
        float w1 = sc_a[1] * (acc[1][r] - mn_a[1]) + bt_a[1];
        float w2 = sc_a[2] * (acc[2][r] - mn_a[2]) + bt_a[2];
        float w3 = sc_a[3] * (acc[3][r] - mn_a[3]) + bt_a[3];
        uint2 o;
        o.x = (unsigned)f2bf(w0) | ((unsigned)f2bf(w1) << 16);
        o.y = (unsigned)f2bf(w2) | ((unsigned)f2bf(w3) << 16);
        *(uint2*)&wkn[(size_t)brow * NB + n0] = o;
    }
}

// ---- fused: blocks 0..255 repack wkn->wkt; blocks 256..1279 transpose x -> xT bf16 -----------
__global__ __launch_bounds__(256) void repack_xt(
    const unsigned short* __restrict__ wkn, unsigned short* __restrict__ wkt,
    const float* __restrict__ x, unsigned short* __restrict__ xb16)
{
    __shared__ char lmem[16 * 580 * 4];
    int t = threadIdx.x;
    if (blockIdx.x < 256) {
        unsigned int* lt = (unsigned int*)lmem;   // [16][580]
        int b = blockIdx.x >> 3;
        int s0 = (blockIdx.x & 7) * 16;
        const unsigned int* src = (const unsigned int*)wkn + ((size_t)b * NB >> 1) + (size_t)s0 * 576;
#pragma unroll
        for (int i = 0; i < 36; i++) {
            int idx = t + i * 256;
            int si = idx / 576;
            int j2 = idx - si * 576;
            lt[si * 580 + j2] = src[(size_t)si * 576 + j2];
        }
        __syncthreads();
        const unsigned short* ls = (const unsigned short*)lt;
#pragma unroll
        for (int i = 0; i < 9; i++) {
            int tau = t + i * 256;
            int half = tau & 1;
            int unit = tau >> 1;
            int uv = unit >> 7;
            int f = unit & 127;
            int col = f * 9 + uv;
            unsigned short v[8];
#pragma unroll
            for (int ss = 0; ss < 8; ss++)
                v[ss] = ls[(half * 8 + ss) * 1160 + col];
            uint4 o;
            o.x = v[0] | ((unsigned)v[1] << 16);
            o.y = v[2] | ((unsigned)v[3] << 16);
            o.z = v[4] | ((unsigned)v[5] << 16);
            o.w = v[6] | ((unsigned)v[7] << 16);
            ((uint4*)wkt)[((((size_t)b * 9 + uv) * 128 + f) * 16) + (s0 >> 3) + half] = o;
        }
    } else {
        unsigned short* lx = (unsigned short*)lmem;   // [32][130]
        int idx = blockIdx.x - 256;
        int p = idx & 31;
        int b = idx >> 5;
        const float* xp = x + (size_t)b * CCH * 1024 + p * 32;
#pragma unroll
        for (int i = 0; i < 16; i++) {
            int ii = t + i * 256;
            int s = ii >> 5;
            int q = ii & 31;
            lx[q * 130 + s] = f2bf(xp[(size_t)s * 1024 + q]);
        }
        __syncthreads();
#pragma unroll
        for (int i = 0; i < 2; i++) {
            int tau = t + i * 256;
            int q = tau >> 4;
            int ch = tau & 15;
            const unsigned short* r = &lx[q * 130 + ch * 8];
            uint4 o;
            o.x = r[0] | ((unsigned)r[1] << 16);
            o.y = r[2] | ((unsigned)r[3] << 16);
            o.z = r[4] | ((unsigned)r[5] << 16);
            o.w = r[6] | ((unsigned)r[7] << 16);
            ((uint4*)xb16)[((((size_t)b * 32 + p) * 32) + q) * 16 + ch] = o;
        }
    }
}

// ---- conv: 256 thr = 4 waves (2 f-halves x 2 row-pairs), p-tile = 4 rows, 256 blocks ----------
// Depth-1 double-buffered A prefetch. XCD-swizzled: 4 samples/XCD (Wk slice L2-resident).
__global__ __launch_bounds__(256) void conv_mfma(
    const float* __restrict__ x, const unsigned short* __restrict__ xb16,
    const unsigned short* __restrict__ wkt, const float* __restrict__ cb,
    float* __restrict__ out)
{
    __shared__ short8 lds8[6 * 34 * 17];      // 55.5 KB: rows p0-1..p0+4, col stride 17 chunks
    int t = threadIdx.x;
    int w = blockIdx.x;                       // 256 blocks
    int xcd = w & 7, slot = w >> 3;
    int b = (xcd << 2) | (slot & 3);
    int p0 = (slot >> 2) * 4;
    int wid = t >> 6, lane = t & 63;
    int fbase = (wid & 1) * 64;
    int rbase = (wid >> 1) * 2;
    int qcol = lane & 31, klane = lane >> 5;

    if (t < 192) {                            // zero halo cols 0 and 33, 6 rows
        int r = t >> 5;
        int col = ((t >> 4) & 1) ? 33 : 0;
        int ch = t & 15;
        short8 zz = { 0, 0, 0, 0, 0, 0, 0, 0 };
        lds8[(r * 34 + col) * 17 + ch] = zz;
    }
    const uint4* xsrc = (const uint4*)xb16;
#pragma unroll
    for (int i = 0; i < 12; i++) {            // stage 6 rows x 32 q x 16 ch = 3072 uint4
        int tau = t + i * 256;
        int ch = tau & 15;
        int q = (tau >> 4) & 31;
        int r = tau >> 9;                     // 0..5
        int prow = p0 - 1 + r;
        uint4 v = make_uint4(0, 0, 0, 0);
        if (prow >= 0 && prow < 32)
            v = xsrc[((((size_t)b * 32 + prow) * 32) + q) * 16 + ch];
        *(uint4*)&lds8[(r * 34 + q + 1) * 17 + ch] = v;
    }
    __syncthreads();

    floatx16 acc[2][2];
#pragma unroll
    for (int mi = 0; mi < 2; mi++)
#pragma unroll
        for (int ni = 0; ni < 2; ni++)
#pragma unroll
            for (int r = 0; r < 16; r++) acc[mi][ni][r] = 0.f;

    const short8* A8 = (const short8*)wkt + ((size_t)b * 9 << 11);
    short8 Abuf0[6], Abuf1[6];

#define LOAD6(BUF, ST)                                                        \
    {                                                                         \
        int v_ = (ST) >> 3, ks_ = (ST) & 7;                                   \
        int ko_ = ks_ * 2 + klane;                                            \
        _Pragma("unroll") for (int u_ = 0; u_ < 3; u_++) {                    \
            const short8* Au_ = A8 + ((size_t)(u_ * 3 + v_) << 11);           \
            BUF[u_ * 2]     = Au_[(fbase + qcol) * 16 + ko_];                 \
            BUF[u_ * 2 + 1] = Au_[(fbase + 32 + qcol) * 16 + ko_];            \
        }                                                                     \
    }
#define COMPUTE(BUF, ST)                                                      \
    {                                                                         \
        int v_ = (ST) >> 3, ks_ = (ST) & 7;                                   \
        int ko_ = ks_ * 2 + klane;                                            \
        short8 br[4];                                                         \
        _Pragma("unroll") for (int r_ = 0; r_ < 4; r_++)                      \
            br[r_] = lds8[((rbase + r_) * 34 + qcol + v_) * 17 + ko_];        \
        _Pragma("unroll") for (int u_ = 0; u_ < 3; u_++) {                    \
            acc[0][0] = __builtin_amdgcn_mfma_f32_32x32x16_bf16(              \
                BUF[u_ * 2], br[u_], acc[0][0], 0, 0, 0);                     \
            acc[0][1] = __builtin_amdgcn_mfma_f32_32x32x16_bf16(              \
                BUF[u_ * 2], br[u_ + 1], acc[0][1], 0, 0, 0);                 \
            acc[1][0] = __builtin_amdgcn_mfma_f32_32x32x16_bf16(              \
                BUF[u_ * 2 + 1], br[u_], acc[1][0], 0, 0, 0);                 \
            acc[1][1] = __builtin_amdgcn_mfma_f32_32x32x16_bf16(              \
                BUF[u_ * 2 + 1], br[u_ + 1], acc[1][1], 0, 0, 0);             \
        }                                                                     \
    }

    LOAD6(Abuf0, 0)
    for (int st = 0; st < 24; st += 2) {
        LOAD6(Abuf1, st + 1)
        COMPUTE(Abuf0, st)
        if (st + 2 < 24) LOAD6(Abuf0, st + 2)
        COMPUTE(Abuf1, st + 1)
    }
#undef LOAD6
#undef COMPUTE

    const size_t xb = (size_t)b * CCH * 1024;
    int prow0 = p0 + rbase;
#pragma unroll
    for (int mi = 0; mi < 2; mi++)
#pragma unroll
    for (int ni = 0; ni < 2; ni++) {
        int p = prow0 + ni;
#pragma unroll
        for (int r = 0; r < 16; r++) {
            int fl = (r & 3) + 8 * (r >> 2) + 4 * klane;
            int f = fbase + mi * 32 + fl;
            size_t idx = xb + (size_t)f * 1024 + p * 32 + qcol;
            out[idx] = acc[mi][ni][r] + x[idx] + cb[f];
        }
    }
}

extern "C" void kernel_launch(void* const* d_in, const int* in_sizes, int n_in,
                              void* d_out, int out_size, void* d_ws, size_t ws_size,
                              hipStream_t stream) {
    const float* x     = (const float*)d_in[0];
    const float* z     = (const float*)d_in[1];
    const float* dw    = (const float*)d_in[2];
    const float* db    = (const float*)d_in[3];
    const float* gamma = (const float*)d_in[4];
    const float* beta  = (const float*)d_in[5];
    const float* cb    = (const float*)d_in[6];
    float* out = (float*)d_out;

    unsigned short* wkn  = (unsigned short*)d_ws;                                       // 9.44 MB
    unsigned short* wkt  = (unsigned short*)((char*)d_ws + (size_t)BSZ * NB * 2);       // 9.44 MB
    unsigned short* xb16 = (unsigned short*)((char*)d_ws + (size_t)BSZ * NB * 4);       // 8.4 MB

    hyper_mfma<<<NB / 128, 64, 0, stream>>>(z, dw, db, gamma, beta, wkn);
    repack_xt<<<256 + 1024, 256, 0, stream>>>(wkn, wkt, x, xb16);
    conv_mfma<<<256, 256, 0, stream>>>(x, xb16, wkt, cb, out);
}